// Round 6
// baseline (183.362 us; speedup 1.0000x reference)
//
#include <hip/hip_runtime.h>
#include <hip/hip_cooperative_groups.h>
#include <hip/hip_bf16.h>
#include <stdint.h>
#include <math.h>

namespace cg = cooperative_groups;

#define B_N 128
#define D_N 512
#define H_N 1024
#define C_N 1000
#define CP  1024   // padded row stride for logits/g
#define NPART 16   // K-split count for fc1 (d) and fc2 (j)
#define BH (B_N * H_N)

// ---------------------------------------------------------------------------
// threefry2x32 (JAX-compatible, 20 rounds) -- verified bit-exact (R1 absmax 0)
// ---------------------------------------------------------------------------
__device__ __forceinline__ uint32_t rotl32(uint32_t v, int r) {
  return (v << r) | (v >> (32 - r));
}

__device__ __forceinline__ void threefry2x32(uint32_t k0, uint32_t k1,
                                             uint32_t x0, uint32_t x1,
                                             uint32_t &o0, uint32_t &o1) {
  uint32_t ks2 = k0 ^ k1 ^ 0x1BD11BDAu;
#define TF_R(r) { x0 += x1; x1 = rotl32(x1, r); x1 ^= x0; }
  x0 += k0; x1 += k1;
  TF_R(13) TF_R(15) TF_R(26) TF_R(6)
  x0 += k1; x1 += ks2 + 1u;
  TF_R(17) TF_R(29) TF_R(16) TF_R(24)
  x0 += ks2; x1 += k0 + 2u;
  TF_R(13) TF_R(15) TF_R(26) TF_R(6)
  x0 += k0; x1 += k1 + 3u;
  TF_R(17) TF_R(29) TF_R(16) TF_R(24)
  x0 += k1; x1 += ks2 + 4u;
  TF_R(13) TF_R(15) TF_R(26) TF_R(6)
  x0 += ks2; x1 += k0 + 5u;
#undef TF_R
  o0 = x0; o1 = x1;
}

__device__ __forceinline__ float gumbel_from_key(uint32_t k0, uint32_t k1, uint32_t i) {
  uint32_t o0, o1;
  threefry2x32(k0, k1, 0u, i, o0, o1);
  uint32_t bits = o0 ^ o1;
  uint32_t fb = (bits >> 9) | 0x3f800000u;
  float f = __uint_as_float(fb) - 1.0f;            // [0, 1)
  const float tiny = 1.1754943508222875e-38f;
  float u = fmaxf(tiny, f * (1.0f - tiny) + tiny); // JAX uniform(minval=tiny)
  return -logf(-logf(u));
}

// ---------------------------------------------------------------------------
// block reductions (512 threads = 8 waves)
// ---------------------------------------------------------------------------
__device__ __forceinline__ float block_sum512(float v, float* red) {
  #pragma unroll
  for (int o = 32; o; o >>= 1) v += __shfl_xor(v, o);
  __syncthreads();
  if ((threadIdx.x & 63) == 0) red[threadIdx.x >> 6] = v;
  __syncthreads();
  return red[0] + red[1] + red[2] + red[3] + red[4] + red[5] + red[6] + red[7];
}

__device__ __forceinline__ float block_max512(float v, float* red) {
  #pragma unroll
  for (int o = 32; o; o >>= 1) v = fmaxf(v, __shfl_xor(v, o));
  __syncthreads();
  if ((threadIdx.x & 63) == 0) red[threadIdx.x >> 6] = v;
  __syncthreads();
  float m = red[0];
  #pragma unroll
  for (int w = 1; w < 8; w++) m = fmaxf(m, red[w]);
  return m;
}

// fma4: a += b * s (componentwise). Function, not macro (R4 lesson: a macro
// parameter named `w` substitutes into the `.w` member access).
__device__ __forceinline__ void fma4(float4 &a, const float4 &b, float s) {
  a.x += b.x * s; a.y += b.y * s; a.z += b.z * s; a.w += b.w * s;
}

// ===========================================================================
// FUSED cooperative kernel: 256 blocks x 512 threads, 5 phases, 4 grid syncs.
// Phase bodies are verbatim R5 kernels, re-indexed onto this grid.
// ===========================================================================
union SMem {
  struct { float xT[2][32 * 20]; } a;                     // fc1: 5.1 KB
  struct { float hT[2][64 * 20]; } c;                     // fc2: 10.2 KB
  struct { float lg[1024]; float red[8]; float redv[8];
           int redi[8]; uint32_t keys[2]; } d;            // sample: ~4.2 KB
  struct { float gs[8 * 1024]; float xq[8];
           float wred[8][2]; } e;                         // bwd1: 32.9 KB
};

__global__ __launch_bounds__(512) void k_fused(
    const float* __restrict__ X,  const float* __restrict__ W1,
    const float* __restrict__ b1, const float* __restrict__ W2,
    const float* __restrict__ b2,
    float* __restrict__ hpart, float* __restrict__ lpart,
    float* __restrict__ g, float* __restrict__ hfinal,
    float* __restrict__ xsq_out, float* __restrict__ samp_part,
    float* __restrict__ bwd_part, float* __restrict__ out) {
  cg::grid_group grid = cg::this_grid();
  __shared__ SMem sm;
  int t = threadIdx.x;
  int bid = blockIdx.x;

  // ---------------- Phase A: fc1 -> hpart (2 units of 256 thr per block) ----
  {
    int sub = t >> 8, tt = t & 255;
    int u = bid * 2 + sub;                 // 0..511
    int cbase = (u & 3) * 256;
    int sbase = ((u >> 2) & 7) * 16;
    int dz = u >> 5;                       // 0..15
    float* xT = sm.a.xT[sub];
    {
      int s = tt >> 4;
      int d2 = (tt & 15) * 2;
      float2 xv = *reinterpret_cast<const float2*>(
          &X[(sbase + s) * D_N + dz * 32 + d2]);
      xT[(d2 + 0) * 20 + s] = xv.x;
      xT[(d2 + 1) * 20 + s] = xv.y;
    }
    __syncthreads();
    int c4 = cbase + (tt & 63) * 4;
    int s4 = (tt >> 6) * 4;
    float4 acc0 = {0,0,0,0}, acc1 = {0,0,0,0}, acc2 = {0,0,0,0}, acc3 = {0,0,0,0};
    const float* W1p = W1 + (size_t)(dz * 32) * H_N + c4;
    float4 wb[4], wn[4];
    #pragma unroll
    for (int i = 0; i < 4; i++)
      wb[i] = *reinterpret_cast<const float4*>(W1p + i * H_N);
    for (int j0 = 0; j0 < 32; j0 += 4) {
      #pragma unroll
      for (int i = 0; i < 4; i++) {
        int jn = j0 + 4 + i; jn = (jn < 32) ? jn : 31;
        wn[i] = *reinterpret_cast<const float4*>(W1p + jn * H_N);
      }
      #pragma unroll
      for (int i = 0; i < 4; i++) {
        float4 xv = *reinterpret_cast<const float4*>(&xT[(j0 + i) * 20 + s4]);
        fma4(acc0, wb[i], xv.x);
        fma4(acc1, wb[i], xv.y);
        fma4(acc2, wb[i], xv.z);
        fma4(acc3, wb[i], xv.w);
      }
      #pragma unroll
      for (int i = 0; i < 4; i++) wb[i] = wn[i];
    }
    float* hp = hpart + (size_t)dz * BH;
    *reinterpret_cast<float4*>(&hp[(sbase + s4 + 0) * H_N + c4]) = acc0;
    *reinterpret_cast<float4*>(&hp[(sbase + s4 + 1) * H_N + c4]) = acc1;
    *reinterpret_cast<float4*>(&hp[(sbase + s4 + 2) * H_N + c4]) = acc2;
    *reinterpret_cast<float4*>(&hp[(sbase + s4 + 3) * H_N + c4]) = acc3;
  }
  grid.sync();

  // ---------------- Phase C: fc2 -> lpart (2 units per block) ---------------
  {
    int sub = t >> 8, tt = t & 255;
    int u = bid * 2 + sub;
    int cbase = (u & 3) * 256;
    int sbase = ((u >> 2) & 7) * 16;
    int kb = u >> 5;
    int jbase = kb * 64;
    float* hT = sm.c.hT[sub];
    #pragma unroll
    for (int k = 0; k < 4; k++) {
      int idx = tt + k * 256;       // 0..1023
      int s = idx >> 6, j = idx & 63;
      float v = b1[jbase + j];
      #pragma unroll
      for (int p = 0; p < NPART; p++)
        v += hpart[(size_t)p * BH + (sbase + s) * H_N + jbase + j];
      hT[j * 20 + s] = fmaxf(v, 0.0f);
    }
    __syncthreads();
    int c4 = cbase + (tt & 63) * 4;
    int s4 = (tt >> 6) * 4;
    if (c4 < C_N) {
      float4 acc0 = {0,0,0,0}, acc1 = {0,0,0,0}, acc2 = {0,0,0,0}, acc3 = {0,0,0,0};
      const float* W2p = W2 + (size_t)jbase * C_N + c4;
      float4 wb[4], wn[4];
      #pragma unroll
      for (int i = 0; i < 4; i++)
        wb[i] = *reinterpret_cast<const float4*>(W2p + (size_t)i * C_N);
      for (int j0 = 0; j0 < 64; j0 += 4) {
        #pragma unroll
        for (int i = 0; i < 4; i++) {
          int jn = j0 + 4 + i; jn = (jn < 64) ? jn : 63;
          wn[i] = *reinterpret_cast<const float4*>(W2p + (size_t)jn * C_N);
        }
        #pragma unroll
        for (int i = 0; i < 4; i++) {
          float4 xv = *reinterpret_cast<const float4*>(&hT[(j0 + i) * 20 + s4]);
          fma4(acc0, wb[i], xv.x);
          fma4(acc1, wb[i], xv.y);
          fma4(acc2, wb[i], xv.z);
          fma4(acc3, wb[i], xv.w);
        }
        #pragma unroll
        for (int i = 0; i < 4; i++) wb[i] = wn[i];
      }
      float* lp = lpart + (size_t)kb * (B_N * CP);
      *reinterpret_cast<float4*>(&lp[(sbase + s4 + 0) * CP + c4]) = acc0;
      *reinterpret_cast<float4*>(&lp[(sbase + s4 + 1) * CP + c4]) = acc1;
      *reinterpret_cast<float4*>(&lp[(sbase + s4 + 2) * CP + c4]) = acc2;
      *reinterpret_cast<float4*>(&lp[(sbase + s4 + 3) * CP + c4]) = acc3;
    }
  }
  grid.sync();

  // ---------------- Phase D: sample (blocks 0..127, verbatim R5) ------------
  if (bid < B_N) {
    float* lg = sm.d.lg;
    float* red = sm.d.red;
    float* redv = sm.d.redv;
    int* redi = sm.d.redi;
    uint32_t* keys = sm.d.keys;
    int b = bid;
    {
      float sA = b2[t];
      float sB = (t + 512 < C_N) ? b2[t + 512] : 0.f;
      #pragma unroll
      for (int p = 0; p < NPART; p++) {
        const float* lp = lpart + (size_t)p * (B_N * CP) + b * CP;
        sA += lp[t];
        if (t + 512 < C_N) sB += lp[t + 512];
      }
      lg[t] = sA;
      if (t + 512 < C_N) lg[t + 512] = sB;
    }
    if (t == 0) {
      uint32_t o0, o1;
      threefry2x32(0u, 42u, 0u, (uint32_t)b, o0, o1);
      keys[0] = o0; keys[1] = o1;
    }
    __syncthreads();
    uint32_t k0 = keys[0], k1 = keys[1];

    // gumbel-argmax over 1000 classes
    float bz = -INFINITY; int bi = 0x7fffffff;
    {
      float z0 = lg[t] + gumbel_from_key(k0, k1, (uint32_t)t);
      bz = z0; bi = t;
      if (t + 512 < C_N) {
        float z1 = lg[t + 512] + gumbel_from_key(k0, k1, (uint32_t)(t + 512));
        if (z1 > bz || (z1 == bz && (t + 512) < bi)) { bz = z1; bi = t + 512; }
      }
    }
    #pragma unroll
    for (int o = 32; o; o >>= 1) {
      float ov = __shfl_xor(bz, o);
      int   oi = __shfl_xor(bi, o);
      if (ov > bz || (ov == bz && oi < bi)) { bz = ov; bi = oi; }
    }
    if ((t & 63) == 0) { redv[t >> 6] = bz; redi[t >> 6] = bi; }
    __syncthreads();
    if (t == 0) {
      #pragma unroll
      for (int w = 1; w < 8; w++) {
        if (redv[w] > redv[0] || (redv[w] == redv[0] && redi[w] < redi[0])) {
          redv[0] = redv[w]; redi[0] = redi[w];
        }
      }
    }
    __syncthreads();
    int y = redi[0];

    // softmax
    float lm = lg[t];
    if (t + 512 < C_N) lm = fmaxf(lm, lg[t + 512]);
    float m = block_max512(lm, red);
    float ea = expf(lg[t] - m);
    float eb = (t + 512 < C_N) ? expf(lg[t + 512] - m) : 0.0f;
    float sum1 = block_sum512(ea + eb, red);
    float inv = 1.0f / sum1;

    float ga  = ea * inv - ((t == y) ? 1.0f : 0.0f);
    float gb2 = eb * inv - (((t + 512) == y) ? 1.0f : 0.0f);
    g[b * CP + t] = ga;
    g[b * CP + t + 512] = (t + 512 < C_N) ? gb2 : 0.0f;
    float gn = ga * ga + ((t + 512 < C_N) ? gb2 * gb2 : 0.0f);
    float tnorm = block_sum512(gn, red);   // ||g||^2

    // reconstruct h (pre-relu), write for bwd1 mask, accumulate ||relu(h)||^2
    float h0 = b1[t];
    float h1 = b1[t + 512];
    #pragma unroll
    for (int p = 0; p < NPART; p++) {
      const float* hp = hpart + (size_t)p * BH + b * H_N;
      h0 += hp[t];
      h1 += hp[t + 512];
    }
    hfinal[b * H_N + t] = h0;
    hfinal[b * H_N + t + 512] = h1;
    float r0 = fmaxf(h0, 0.f), r1 = fmaxf(h1, 0.f);
    float hsq = block_sum512(r0 * r0 + r1 * r1, red);

    float xv = (t < D_N) ? X[b * D_N + t] : 0.0f;
    float xsq = block_sum512(xv * xv, red);

    if (t == 0) {
      xsq_out[b] = xsq;
      samp_part[b * 2 + 0] = hsq * tnorm;
      samp_part[b * 2 + 1] = tnorm;
    }
  }
  grid.sync();

  // ---------------- Phase E: bwd1 (4 j-tiles per block, gs staged once) -----
  {
    int sg = bid & 15, jg = bid >> 4;
    int sbase = sg * 8;
    float* gs = sm.e.gs;
    float* xq = sm.e.xq;
    #pragma unroll
    for (int k = 0; k < 16; k++) {
      int idx = t + k * 512;            // 0..8191
      gs[idx] = g[(sbase + (idx >> 10)) * CP + (idx & 1023)];
    }
    if (t < 8) xq[t] = xsq_out[sbase + t];
    __syncthreads();

    int w = t >> 6, lane = t & 63;
    float cb = 0.f, cw = 0.f;
    for (int it2 = 0; it2 < 4; it2++) {
      int jb = (jg * 4 + it2) * 16;
      int j0 = jb + w * 2, j1 = j0 + 1;
      float a0[8] = {0,0,0,0,0,0,0,0};
      float a1[8] = {0,0,0,0,0,0,0,0};
      const float* w2r0 = W2 + (size_t)j0 * C_N;
      const float* w2r1 = W2 + (size_t)j1 * C_N;
      #pragma unroll
      for (int it = 0; it < 4; it++) {
        int c0 = it * 256 + lane * 4;
        bool act = (c0 < C_N);
        float4 wv0 = act ? *reinterpret_cast<const float4*>(w2r0 + c0)
                         : make_float4(0.f, 0.f, 0.f, 0.f);
        float4 wv1 = act ? *reinterpret_cast<const float4*>(w2r1 + c0)
                         : make_float4(0.f, 0.f, 0.f, 0.f);
        #pragma unroll
        for (int s = 0; s < 8; s++) {
          float4 gv = *reinterpret_cast<const float4*>(&gs[s * 1024 + c0]);
          a0[s] += wv0.x * gv.x + wv0.y * gv.y + wv0.z * gv.z + wv0.w * gv.w;
          a1[s] += wv1.x * gv.x + wv1.y * gv.y + wv1.z * gv.z + wv1.w * gv.w;
        }
      }
      #pragma unroll
      for (int off = 32; off; off >>= 1) {
        #pragma unroll
        for (int s = 0; s < 8; s++) {
          a0[s] += __shfl_xor(a0[s], off);
          a1[s] += __shfl_xor(a1[s], off);
        }
      }
      #pragma unroll
      for (int s = 0; s < 8; s++) {
        float h0 = hfinal[(sbase + s) * H_N + j0];
        float h1 = hfinal[(sbase + s) * H_N + j1];
        float v0 = (h0 > 0.f) ? a0[s] : 0.f;
        float v1 = (h1 > 0.f) ? a1[s] : 0.f;
        float q = v0 * v0 + v1 * v1;
        cb += q;
        cw += xq[s] * q;
      }
    }
    if (lane == 0) { sm.e.wred[w][0] = cw; sm.e.wred[w][1] = cb; }
    __syncthreads();
    if (t == 0) {
      float sw = 0.f, sb = 0.f;
      #pragma unroll
      for (int i = 0; i < 8; i++) { sw += sm.e.wred[i][0]; sb += sm.e.wred[i][1]; }
      bwd_part[bid * 2 + 0] = sw;
      bwd_part[bid * 2 + 1] = sb;
    }
  }
  grid.sync();

  // ---------------- Phase F: final reduction (block 0) ----------------------
  if (bid == 0) {
    float* red = sm.d.red;
    float w1v = (t < 256) ? bwd_part[t * 2 + 0] : 0.f;
    float b1v = (t < 256) ? bwd_part[t * 2 + 1] : 0.f;
    float w2v = (t < B_N) ? samp_part[t * 2 + 0] : 0.f;
    float b2v = (t < B_N) ? samp_part[t * 2 + 1] : 0.f;
    w1v = block_sum512(w1v, red);
    b1v = block_sum512(b1v, red);
    w2v = block_sum512(w2v, red);
    b2v = block_sum512(b2v, red);
    if (t == 0) {
      w1v /= 128.0f; b1v /= 128.0f; w2v /= 128.0f; b2v /= 128.0f;
      out[0] = w1v + b1v + w2v + b2v;
      out[1] = w1v;
      out[2] = b1v;
      out[3] = w2v;
      out[4] = b2v;
    }
  }
}

// ===========================================================================
// Fallback path: the proven R5 5-kernel pipeline (used only if cooperative
// launch is unavailable / fails under graph capture).
// ===========================================================================
__global__ __launch_bounds__(256) void k_fc1(const float* __restrict__ X,
                                             const float* __restrict__ W1,
                                             float* __restrict__ hpart) {
  __shared__ float xT[32 * 20];
  int cbase = blockIdx.x * 256;
  int sbase = blockIdx.y * 16;
  int dz = blockIdx.z;
  int t = threadIdx.x;
  {
    int s = t >> 4;
    int d2 = (t & 15) * 2;
    float2 xv = *reinterpret_cast<const float2*>(
        &X[(sbase + s) * D_N + dz * 32 + d2]);
    xT[(d2 + 0) * 20 + s] = xv.x;
    xT[(d2 + 1) * 20 + s] = xv.y;
  }
  __syncthreads();
  int c4 = cbase + (t & 63) * 4;
  int s4 = (t >> 6) * 4;
  float4 acc0 = {0,0,0,0}, acc1 = {0,0,0,0}, acc2 = {0,0,0,0}, acc3 = {0,0,0,0};
  const float* W1p = W1 + (size_t)(dz * 32) * H_N + c4;
  float4 wb[4], wn[4];
  #pragma unroll
  for (int i = 0; i < 4; i++)
    wb[i] = *reinterpret_cast<const float4*>(W1p + i * H_N);
  for (int j0 = 0; j0 < 32; j0 += 4) {
    #pragma unroll
    for (int i = 0; i < 4; i++) {
      int jn = j0 + 4 + i; jn = (jn < 32) ? jn : 31;
      wn[i] = *reinterpret_cast<const float4*>(W1p + jn * H_N);
    }
    #pragma unroll
    for (int i = 0; i < 4; i++) {
      float4 xv = *reinterpret_cast<const float4*>(&xT[(j0 + i) * 20 + s4]);
      fma4(acc0, wb[i], xv.x);
      fma4(acc1, wb[i], xv.y);
      fma4(acc2, wb[i], xv.z);
      fma4(acc3, wb[i], xv.w);
    }
    #pragma unroll
    for (int i = 0; i < 4; i++) wb[i] = wn[i];
  }
  float* hp = hpart + (size_t)dz * BH;
  *reinterpret_cast<float4*>(&hp[(sbase + s4 + 0) * H_N + c4]) = acc0;
  *reinterpret_cast<float4*>(&hp[(sbase + s4 + 1) * H_N + c4]) = acc1;
  *reinterpret_cast<float4*>(&hp[(sbase + s4 + 2) * H_N + c4]) = acc2;
  *reinterpret_cast<float4*>(&hp[(sbase + s4 + 3) * H_N + c4]) = acc3;
}

__global__ __launch_bounds__(256) void k_fc2(const float* __restrict__ hpart,
                                             const float* __restrict__ b1,
                                             const float* __restrict__ W2,
                                             float* __restrict__ lpart) {
  __shared__ float hT[64 * 20];
  int cbase = blockIdx.x * 256;
  int sbase = blockIdx.y * 16;
  int kb = blockIdx.z;
  int jbase = kb * 64;
  int t = threadIdx.x;
  #pragma unroll
  for (int k = 0; k < 4; k++) {
    int idx = t + k * 256;
    int s = idx >> 6, j = idx & 63;
    float v = b1[jbase + j];
    #pragma unroll
    for (int p = 0; p < NPART; p++)
      v += hpart[(size_t)p * BH + (sbase + s) * H_N + jbase + j];
    hT[j * 20 + s] = fmaxf(v, 0.0f);
  }
  __syncthreads();
  int c4 = cbase + (t & 63) * 4;
  int s4 = (t >> 6) * 4;
  if (c4 < C_N) {
    float4 acc0 = {0,0,0,0}, acc1 = {0,0,0,0}, acc2 = {0,0,0,0}, acc3 = {0,0,0,0};
    const float* W2p = W2 + (size_t)jbase * C_N + c4;
    float4 wb[4], wn[4];
    #pragma unroll
    for (int i = 0; i < 4; i++)
      wb[i] = *reinterpret_cast<const float4*>(W2p + (size_t)i * C_N);
    for (int j0 = 0; j0 < 64; j0 += 4) {
      #pragma unroll
      for (int i = 0; i < 4; i++) {
        int jn = j0 + 4 + i; jn = (jn < 64) ? jn : 63;
        wn[i] = *reinterpret_cast<const float4*>(W2p + (size_t)jn * C_N);
      }
      #pragma unroll
      for (int i = 0; i < 4; i++) {
        float4 xv = *reinterpret_cast<const float4*>(&hT[(j0 + i) * 20 + s4]);
        fma4(acc0, wb[i], xv.x);
        fma4(acc1, wb[i], xv.y);
        fma4(acc2, wb[i], xv.z);
        fma4(acc3, wb[i], xv.w);
      }
      #pragma unroll
      for (int i = 0; i < 4; i++) wb[i] = wn[i];
    }
    float* lp = lpart + (size_t)kb * (B_N * CP);
    *reinterpret_cast<float4*>(&lp[(sbase + s4 + 0) * CP + c4]) = acc0;
    *reinterpret_cast<float4*>(&lp[(sbase + s4 + 1) * CP + c4]) = acc1;
    *reinterpret_cast<float4*>(&lp[(sbase + s4 + 2) * CP + c4]) = acc2;
    *reinterpret_cast<float4*>(&lp[(sbase + s4 + 3) * CP + c4]) = acc3;
  }
}

__global__ __launch_bounds__(512) void k_sample(const float* __restrict__ X,
                                                const float* __restrict__ hpart,
                                                const float* __restrict__ b1,
                                                const float* __restrict__ lpart,
                                                const float* __restrict__ b2,
                                                float* __restrict__ g,
                                                float* __restrict__ hfinal,
                                                float* __restrict__ xsq_out,
                                                float* __restrict__ samp_part) {
  __shared__ float lg[C_N];
  __shared__ float red[8];
  __shared__ float redv[8];
  __shared__ int   redi[8];
  __shared__ uint32_t keys[2];
  int b = blockIdx.x;
  int t = threadIdx.x;
  {
    float sA = b2[t];
    float sB = (t + 512 < C_N) ? b2[t + 512] : 0.f;
    #pragma unroll
    for (int p = 0; p < NPART; p++) {
      const float* lp = lpart + (size_t)p * (B_N * CP) + b * CP;
      sA += lp[t];
      if (t + 512 < C_N) sB += lp[t + 512];
    }
    lg[t] = sA;
    if (t + 512 < C_N) lg[t + 512] = sB;
  }
  if (t == 0) {
    uint32_t o0, o1;
    threefry2x32(0u, 42u, 0u, (uint32_t)b, o0, o1);
    keys[0] = o0; keys[1] = o1;
  }
  __syncthreads();
  uint32_t k0 = keys[0], k1 = keys[1];
  float bz = -INFINITY; int bi = 0x7fffffff;
  {
    float z0 = lg[t] + gumbel_from_key(k0, k1, (uint32_t)t);
    bz = z0; bi = t;
    if (t + 512 < C_N) {
      float z1 = lg[t + 512] + gumbel_from_key(k0, k1, (uint32_t)(t + 512));
      if (z1 > bz || (z1 == bz && (t + 512) < bi)) { bz = z1; bi = t + 512; }
    }
  }
  #pragma unroll
  for (int o = 32; o; o >>= 1) {
    float ov = __shfl_xor(bz, o);
    int   oi = __shfl_xor(bi, o);
    if (ov > bz || (ov == bz && oi < bi)) { bz = ov; bi = oi; }
  }
  if ((t & 63) == 0) { redv[t >> 6] = bz; redi[t >> 6] = bi; }
  __syncthreads();
  if (t == 0) {
    #pragma unroll
    for (int w = 1; w < 8; w++) {
      if (redv[w] > redv[0] || (redv[w] == redv[0] && redi[w] < redi[0])) {
        redv[0] = redv[w]; redi[0] = redi[w];
      }
    }
  }
  __syncthreads();
  int y = redi[0];
  float lm = lg[t];
  if (t + 512 < C_N) lm = fmaxf(lm, lg[t + 512]);
  float m = block_max512(lm, red);
  float ea = expf(lg[t] - m);
  float eb = (t + 512 < C_N) ? expf(lg[t + 512] - m) : 0.0f;
  float sum1 = block_sum512(ea + eb, red);
  float inv = 1.0f / sum1;
  float ga  = ea * inv - ((t == y) ? 1.0f : 0.0f);
  float gb2 = eb * inv - (((t + 512) == y) ? 1.0f : 0.0f);
  g[b * CP + t] = ga;
  g[b * CP + t + 512] = (t + 512 < C_N) ? gb2 : 0.0f;
  float gn = ga * ga + ((t + 512 < C_N) ? gb2 * gb2 : 0.0f);
  float tnorm = block_sum512(gn, red);
  float h0 = b1[t];
  float h1 = b1[t + 512];
  #pragma unroll
  for (int p = 0; p < NPART; p++) {
    const float* hp = hpart + (size_t)p * BH + b * H_N;
    h0 += hp[t];
    h1 += hp[t + 512];
  }
  hfinal[b * H_N + t] = h0;
  hfinal[b * H_N + t + 512] = h1;
  float r0 = fmaxf(h0, 0.f), r1 = fmaxf(h1, 0.f);
  float hsq = block_sum512(r0 * r0 + r1 * r1, red);
  float xv = (t < D_N) ? X[b * D_N + t] : 0.0f;
  float xsq = block_sum512(xv * xv, red);
  if (t == 0) {
    xsq_out[b] = xsq;
    samp_part[b * 2 + 0] = hsq * tnorm;
    samp_part[b * 2 + 1] = tnorm;
  }
}

__global__ __launch_bounds__(512) void k_bwd1(const float* __restrict__ g,
                                              const float* __restrict__ W2,
                                              const float* __restrict__ hfinal,
                                              const float* __restrict__ xsq,
                                              float* __restrict__ bwd_part) {
  __shared__ float gs[8 * 1024];
  __shared__ float xq[8];
  __shared__ float wred[8][2];
  int jb = blockIdx.x * 16;
  int sbase = blockIdx.y * 8;
  int t = threadIdx.x;
  #pragma unroll
  for (int k = 0; k < 16; k++) {
    int idx = t + k * 512;
    gs[idx] = g[(sbase + (idx >> 10)) * CP + (idx & 1023)];
  }
  if (t < 8) xq[t] = xsq[sbase + t];
  __syncthreads();
  int w = t >> 6, lane = t & 63;
  int j0 = jb + w * 2, j1 = j0 + 1;
  float a0[8] = {0,0,0,0,0,0,0,0};
  float a1[8] = {0,0,0,0,0,0,0,0};
  const float* w2r0 = W2 + (size_t)j0 * C_N;
  const float* w2r1 = W2 + (size_t)j1 * C_N;
  #pragma unroll
  for (int it = 0; it < 4; it++) {
    int c0 = it * 256 + lane * 4;
    bool act = (c0 < C_N);
    float4 wv0 = act ? *reinterpret_cast<const float4*>(w2r0 + c0)
                     : make_float4(0.f, 0.f, 0.f, 0.f);
    float4 wv1 = act ? *reinterpret_cast<const float4*>(w2r1 + c0)
                     : make_float4(0.f, 0.f, 0.f, 0.f);
    #pragma unroll
    for (int s = 0; s < 8; s++) {
      float4 gv = *reinterpret_cast<const float4*>(&gs[s * 1024 + c0]);
      a0[s] += wv0.x * gv.x + wv0.y * gv.y + wv0.z * gv.z + wv0.w * gv.w;
      a1[s] += wv1.x * gv.x + wv1.y * gv.y + wv1.z * gv.z + wv1.w * gv.w;
    }
  }
  #pragma unroll
  for (int off = 32; off; off >>= 1) {
    #pragma unroll
    for (int s = 0; s < 8; s++) {
      a0[s] += __shfl_xor(a0[s], off);
      a1[s] += __shfl_xor(a1[s], off);
    }
  }
  float cb = 0.f, cw = 0.f;
  #pragma unroll
  for (int s = 0; s < 8; s++) {
    float h0 = hfinal[(sbase + s) * H_N + j0];
    float h1 = hfinal[(sbase + s) * H_N + j1];
    float v0 = (h0 > 0.f) ? a0[s] : 0.f;
    float v1 = (h1 > 0.f) ? a1[s] : 0.f;
    float q = v0 * v0 + v1 * v1;
    cb += q;
    cw += xq[s] * q;
  }
  if (lane == 0) { wred[w][0] = cw; wred[w][1] = cb; }
  __syncthreads();
  if (t == 0) {
    float sw = 0.f, sb = 0.f;
    #pragma unroll
    for (int i = 0; i < 8; i++) { sw += wred[i][0]; sb += wred[i][1]; }
    int bid = blockIdx.y * 64 + blockIdx.x;
    bwd_part[bid * 2 + 0] = sw;
    bwd_part[bid * 2 + 1] = sb;
  }
}

__global__ __launch_bounds__(512) void k_final(const float* __restrict__ samp_part,
                                               const float* __restrict__ bwd_part,
                                               float* __restrict__ out) {
  __shared__ float red[8];
  int t = threadIdx.x;
  float w1v = bwd_part[t * 2 + 0] + bwd_part[(t + 512) * 2 + 0];
  float b1v = bwd_part[t * 2 + 1] + bwd_part[(t + 512) * 2 + 1];
  float w2v = (t < B_N) ? samp_part[t * 2 + 0] : 0.f;
  float b2v = (t < B_N) ? samp_part[t * 2 + 1] : 0.f;
  w1v = block_sum512(w1v, red);
  b1v = block_sum512(b1v, red);
  w2v = block_sum512(w2v, red);
  b2v = block_sum512(b2v, red);
  if (t == 0) {
    w1v /= 128.0f; b1v /= 128.0f; w2v /= 128.0f; b2v /= 128.0f;
    out[0] = w1v + b1v + w2v + b2v;
    out[1] = w1v;
    out[2] = b1v;
    out[3] = w2v;
    out[4] = b2v;
  }
}

// ---------------------------------------------------------------------------
extern "C" void kernel_launch(void* const* d_in, const int* in_sizes, int n_in,
                              void* d_out, int out_size, void* d_ws, size_t ws_size,
                              hipStream_t stream) {
  const float* X  = (const float*)d_in[0];
  const float* W1 = (const float*)d_in[1];
  const float* b1 = (const float*)d_in[2];
  const float* W2 = (const float*)d_in[3];
  const float* b2 = (const float*)d_in[4];
  float* out = (float*)d_out;

  float* ws        = (float*)d_ws;
  float* hpart     = ws;                        // NPART * 131072
  float* lpart     = hpart + NPART * BH;        // NPART * 131072
  float* g         = lpart + NPART * (B_N*CP);  // 131072 (stride 1024, padded)
  float* hfinal    = g + (B_N * CP);            // 131072
  float* xsq       = hfinal + BH;               // 128
  float* samp_part = xsq + 128;                 // 256
  float* bwd_part  = samp_part + 256;           // 512

  void* args[] = {(void*)&X, (void*)&W1, (void*)&b1, (void*)&W2, (void*)&b2,
                  (void*)&hpart, (void*)&lpart, (void*)&g, (void*)&hfinal,
                  (void*)&xsq, (void*)&samp_part, (void*)&bwd_part, (void*)&out};
  hipError_t err = hipLaunchCooperativeKernel((void*)k_fused, dim3(256), dim3(512),
                                              args, 0, stream);
  if (err != hipSuccess) {
    // fallback: proven R5 5-kernel pipeline
    k_fc1<<<dim3(4, 8, NPART), 256, 0, stream>>>(X, W1, hpart);
    k_fc2<<<dim3(4, 8, NPART), 256, 0, stream>>>(hpart, b1, W2, lpart);
    k_sample<<<B_N, 512, 0, stream>>>(X, hpart, b1, lpart, b2, g, hfinal, xsq, samp_part);
    k_bwd1<<<dim3(64, 16), 512, 0, stream>>>(g, W2, hfinal, xsq, bwd_part);
    k_final<<<1, 512, 0, stream>>>(samp_part, bwd_part, out);
  }
}

// Round 7
// 101.795 us; speedup vs baseline: 1.8013x; 1.8013x over previous
//
#include <hip/hip_runtime.h>
#include <hip/hip_bf16.h>
#include <stdint.h>
#include <math.h>

#define B_N 128
#define D_N 512
#define H_N 1024
#define C_N 1000
#define CP  1024                 // padded row stride for logit partials / g
#define NJT 8                    // fc2 j-split
#define LP_STRIDE (B_N * CP)     // one logit-partial plane

// ---------------------------------------------------------------------------
// threefry2x32 (JAX-compatible, 20 rounds) -- verified bit-exact (R1 absmax 0)
// ---------------------------------------------------------------------------
__device__ __forceinline__ uint32_t rotl32(uint32_t v, int r) {
  return (v << r) | (v >> (32 - r));
}

__device__ __forceinline__ void threefry2x32(uint32_t k0, uint32_t k1,
                                             uint32_t x0, uint32_t x1,
                                             uint32_t &o0, uint32_t &o1) {
  uint32_t ks2 = k0 ^ k1 ^ 0x1BD11BDAu;
#define TF_R(r) { x0 += x1; x1 = rotl32(x1, r); x1 ^= x0; }
  x0 += k0; x1 += k1;
  TF_R(13) TF_R(15) TF_R(26) TF_R(6)
  x0 += k1; x1 += ks2 + 1u;
  TF_R(17) TF_R(29) TF_R(16) TF_R(24)
  x0 += ks2; x1 += k0 + 2u;
  TF_R(13) TF_R(15) TF_R(26) TF_R(6)
  x0 += k0; x1 += k1 + 3u;
  TF_R(17) TF_R(29) TF_R(16) TF_R(24)
  x0 += k1; x1 += ks2 + 4u;
  TF_R(13) TF_R(15) TF_R(26) TF_R(6)
  x0 += ks2; x1 += k0 + 5u;
#undef TF_R
  o0 = x0; o1 = x1;
}

__device__ __forceinline__ float gumbel_from_key(uint32_t k0, uint32_t k1, uint32_t i) {
  uint32_t o0, o1;
  threefry2x32(k0, k1, 0u, i, o0, o1);
  uint32_t bits = o0 ^ o1;
  uint32_t fb = (bits >> 9) | 0x3f800000u;
  float f = __uint_as_float(fb) - 1.0f;            // [0, 1)
  const float tiny = 1.1754943508222875e-38f;
  float u = fmaxf(tiny, f * (1.0f - tiny) + tiny); // JAX uniform(minval=tiny)
  return -logf(-logf(u));
}

// ---------------------------------------------------------------------------
__device__ __forceinline__ float wave_sum(float v) {
  #pragma unroll
  for (int o = 32; o; o >>= 1) v += __shfl_xor(v, o);
  return v;
}

__device__ __forceinline__ float block_sum512(float v, float* red) {
  #pragma unroll
  for (int o = 32; o; o >>= 1) v += __shfl_xor(v, o);
  __syncthreads();
  if ((threadIdx.x & 63) == 0) red[threadIdx.x >> 6] = v;
  __syncthreads();
  return red[0] + red[1] + red[2] + red[3] + red[4] + red[5] + red[6] + red[7];
}

// fma4: a += b * s (function, not macro: R4 lesson -- macro param `w` would
// substitute into the `.w` member access).
__device__ __forceinline__ void fma4(float4 &a, const float4 &b, float s) {
  a.x += b.x * s; a.y += b.y * s; a.z += b.z * s; a.w += b.w * s;
}

// ---------------------------------------------------------------------------
// K1: hfinal[128][1024] = X @ W1 + b1 (full K, no partials).
// grid 256 = ct(8: 128c) x sg(32: 4s); 256 thr, thread = 1c x 2s.
// Also: ct==0 blocks compute xsq (X already staged in LDS); block 0 zeroes
// the mega-kernel arrival counter (visible via kernel-boundary release).
// ---------------------------------------------------------------------------
__global__ __launch_bounds__(256) void k_fc1(const float* __restrict__ X,
                                             const float* __restrict__ W1,
                                             const float* __restrict__ b1,
                                             float* __restrict__ hfinal,
                                             float* __restrict__ xsq,
                                             unsigned int* __restrict__ counter) {
  __shared__ float xs[4 * D_N];   // 8 KB, [s][d]
  int bid = blockIdx.x;
  int ct = bid & 7, sg = bid >> 3;
  int cbase = ct * 128, sbase = sg * 4;
  int t = threadIdx.x;
  if (bid == 0 && t == 0) *counter = 0u;   // reset arrival counter for k_mega
  #pragma unroll
  for (int k = 0; k < 2; k++) {
    int idx4 = t + k * 256;                // 0..511 float4s
    int s = idx4 >> 7, dq = idx4 & 127;
    *reinterpret_cast<float4*>(&xs[s * D_N + dq * 4]) =
        *reinterpret_cast<const float4*>(&X[(sbase + s) * D_N + dq * 4]);
  }
  __syncthreads();

  int c0 = cbase + (t & 127);
  int spair = (t >> 7) * 2;                // 0 or 2
  const float* W1c = W1 + c0;
  const float* x0p = &xs[(spair + 0) * D_N];
  const float* x1p = &xs[(spair + 1) * D_N];
  float a0 = 0.f, a1 = 0.f;
  float wA[8], wB[8];
  #pragma unroll
  for (int i = 0; i < 8; i++) wA[i] = W1c[(size_t)i * H_N];
  for (int d0 = 0; d0 < D_N; d0 += 16) {
    #pragma unroll
    for (int i = 0; i < 8; i++) wB[i] = W1c[(size_t)((d0 + 8 + i) & (D_N - 1)) * H_N];
    #pragma unroll
    for (int i = 0; i < 8; i++) { a0 += wA[i] * x0p[d0 + i]; a1 += wA[i] * x1p[d0 + i]; }
    #pragma unroll
    for (int i = 0; i < 8; i++) wA[i] = W1c[(size_t)((d0 + 16 + i) & (D_N - 1)) * H_N];
    #pragma unroll
    for (int i = 0; i < 8; i++) { a0 += wB[i] * x0p[d0 + 8 + i]; a1 += wB[i] * x1p[d0 + 8 + i]; }
  }
  float bb = b1[c0];
  hfinal[(size_t)(sbase + spair + 0) * H_N + c0] = a0 + bb;
  hfinal[(size_t)(sbase + spair + 1) * H_N + c0] = a1 + bb;

  if (ct == 0) {                           // xsq for this block's 4 samples
    int s = t >> 6, l = t & 63;            // wave per sample
    float v = 0.f;
    #pragma unroll
    for (int k = 0; k < 8; k++) { float xv = xs[s * D_N + l + k * 64]; v += xv * xv; }
    v = wave_sum(v);
    if (l == 0) xsq[sbase + s] = v;
  }
}

// ---------------------------------------------------------------------------
// K2: lpart[jt][s][c] = partial of relu(hfinal) @ W2 over j in [jt*128,+128).
// grid 256 = ct(4: 256c) x sg(8: 16s) x jt(8); 256 thr, thread = 4c x 4s
// (R5-proven shape). b2 applied in k_mega. Last c-tile clamps W2 reads to
// stay in bounds; pad columns [1000,1024) of lpart hold garbage, never read.
// ---------------------------------------------------------------------------
__global__ __launch_bounds__(256) void k_fc2(const float* __restrict__ hfinal,
                                             const float* __restrict__ W2,
                                             float* __restrict__ lpart) {
  __shared__ float hT[128 * 20];  // [j][s], stride 20 (float4-aligned at s4)
  int bid = blockIdx.x;
  int ct = bid & 3, sg = (bid >> 2) & 7, jt = bid >> 5;
  int cbase = ct * 256, sbase = sg * 16, jbase = jt * 128;
  int t = threadIdx.x;
  #pragma unroll
  for (int k = 0; k < 8; k++) {
    int idx = t + k * 256;        // 0..2047
    int s = idx >> 7, j = idx & 127;
    hT[j * 20 + s] = fmaxf(hfinal[(size_t)(sbase + s) * H_N + jbase + j], 0.0f);
  }
  __syncthreads();
  int c4 = cbase + (t & 63) * 4;
  int s4 = (t >> 6) * 4;
  int cr = (c4 <= C_N - 4) ? c4 : (C_N - 4);   // clamp reads; writes stay at c4
  float4 acc0 = {0,0,0,0}, acc1 = {0,0,0,0}, acc2 = {0,0,0,0}, acc3 = {0,0,0,0};
  const float* W2c = W2 + (size_t)jbase * C_N + cr;
  float4 wb[4], wn[4];
  #pragma unroll
  for (int i = 0; i < 4; i++)
    wb[i] = *reinterpret_cast<const float4*>(W2c + (size_t)i * C_N);
  for (int j0 = 0; j0 < 128; j0 += 4) {
    #pragma unroll
    for (int i = 0; i < 4; i++) {
      int jn = j0 + 4 + i; jn = (jn < 128) ? jn : 127;
      wn[i] = *reinterpret_cast<const float4*>(W2c + (size_t)jn * C_N);
    }
    #pragma unroll
    for (int i = 0; i < 4; i++) {
      float4 xv = *reinterpret_cast<const float4*>(&hT[(j0 + i) * 20 + s4]);
      fma4(acc0, wb[i], xv.x);
      fma4(acc1, wb[i], xv.y);
      fma4(acc2, wb[i], xv.z);
      fma4(acc3, wb[i], xv.w);
    }
    #pragma unroll
    for (int i = 0; i < 4; i++) wb[i] = wn[i];
  }
  float* lp = lpart + (size_t)jt * LP_STRIDE;
  *reinterpret_cast<float4*>(&lp[(size_t)(sbase + s4 + 0) * CP + c4]) = acc0;
  *reinterpret_cast<float4*>(&lp[(size_t)(sbase + s4 + 1) * CP + c4]) = acc1;
  *reinterpret_cast<float4*>(&lp[(size_t)(sbase + s4 + 2) * CP + c4]) = acc2;
  *reinterpret_cast<float4*>(&lp[(size_t)(sbase + s4 + 3) * CP + c4]) = acc3;
}

// ---------------------------------------------------------------------------
// K3 (mega): grid 256 = sg(16: 8 samples) x jt(16: 64 j-rows); 512 thr.
// Each block: (a) wave w recomputes sampling for its sample S=sg*8+w fully
// in-wave (threefry bit-exact => all jt blocks agree on y); g kept in LDS.
// (b) backward slice: ghat for 64 j-rows x 8 samples, masked, squared,
// accumulated into per-block partials. (c) jt==0 blocks also produce the
// per-sample-group W2/b2 trace partials. (d) 256th arriver (ACQ_REL atomic,
// no spinning) reduces all partials in fixed index order -> out[5].
// ---------------------------------------------------------------------------
__global__ __launch_bounds__(512) void k_mega(const float* __restrict__ lpart,
                                              const float* __restrict__ b2,
                                              const float* __restrict__ W2,
                                              const float* __restrict__ hfinal,
                                              const float* __restrict__ xsq_g,
                                              float* __restrict__ samp_part,
                                              float* __restrict__ bwd_part,
                                              unsigned int* __restrict__ counter,
                                              float* __restrict__ out) {
  __shared__ float lg[8 * 1024];   // g, zero-padded cols [1000,1024)
  __shared__ float tnormS[8], hsqS[8], xq[8];
  __shared__ float wred[8][2];
  __shared__ float red[8];
  __shared__ int isLast;
  int bid = blockIdx.x;
  int sg = bid & 15, jt = bid >> 4;
  int sbase = sg * 8, jbase = jt * 64;
  int t = threadIdx.x, w = t >> 6, lane = t & 63;
  int S = sbase + w;               // this wave's sample

  // --- (a) sampling, wave-local (16 classes/lane) ---
  uint32_t kk0, kk1;
  threefry2x32(0u, 42u, 0u, (uint32_t)S, kk0, kk1);
  float v[16];
  float bz = -INFINITY; int bi = 0x7fffffff;
  #pragma unroll
  for (int k = 0; k < 16; k++) {
    int c = lane + k * 64;
    float val = -INFINITY;
    if (c < C_N) {
      val = b2[c];
      #pragma unroll
      for (int p = 0; p < NJT; p++)
        val += lpart[(size_t)p * LP_STRIDE + (size_t)S * CP + c];
      float z = val + gumbel_from_key(kk0, kk1, (uint32_t)c);
      if (z > bz || (z == bz && c < bi)) { bz = z; bi = c; }
    }
    v[k] = val;
  }
  #pragma unroll
  for (int o = 32; o; o >>= 1) {
    float ov = __shfl_xor(bz, o); int oi = __shfl_xor(bi, o);
    if (ov > bz || (ov == bz && oi < bi)) { bz = ov; bi = oi; }
  }
  int y = bi;
  float m = v[0];
  #pragma unroll
  for (int k = 1; k < 16; k++) m = fmaxf(m, v[k]);
  #pragma unroll
  for (int o = 32; o; o >>= 1) m = fmaxf(m, __shfl_xor(m, o));
  float sum = 0.f;
  #pragma unroll
  for (int k = 0; k < 16; k++) { v[k] = expf(v[k] - m); sum += v[k]; }
  sum = wave_sum(sum);
  float inv = 1.0f / sum;
  float tn = 0.f;
  #pragma unroll
  for (int k = 0; k < 16; k++) {
    int c = lane + k * 64;
    float gv = v[k] * inv - ((c == y) ? 1.0f : 0.0f);
    if (c >= C_N) gv = 0.f;        // pad columns exactly zero
    lg[w * 1024 + c] = gv;
    tn += gv * gv;
  }
  tn = wave_sum(tn);
  if (lane == 0) tnormS[w] = tn;
  if (t < 8) xq[t] = xsq_g[sbase + t];
  if (jt == 0) {                   // ||relu(h)||^2 per sample, wave-local
    float hv = 0.f;
    #pragma unroll
    for (int k = 0; k < 16; k++) {
      float hh = hfinal[(size_t)S * H_N + lane + k * 64];
      float r = fmaxf(hh, 0.f);
      hv += r * r;
    }
    hv = wave_sum(hv);
    if (lane == 0) hsqS[w] = hv;
  }
  __syncthreads();

  // --- (b) backward: 64 j-rows, 8 samples ---
  float cb = 0.f, cw = 0.f;
  for (int it2 = 0; it2 < 4; it2++) {
    int jb = jbase + it2 * 16;
    int j0 = jb + w * 2, j1 = j0 + 1;
    float a0[8] = {0,0,0,0,0,0,0,0};
    float a1[8] = {0,0,0,0,0,0,0,0};
    const float* w2r0 = W2 + (size_t)j0 * C_N;
    const float* w2r1 = W2 + (size_t)j1 * C_N;
    #pragma unroll
    for (int it = 0; it < 4; it++) {
      int c0 = it * 256 + lane * 4;
      bool act = (c0 < C_N);
      float4 wv0 = act ? *reinterpret_cast<const float4*>(w2r0 + c0)
                       : make_float4(0.f, 0.f, 0.f, 0.f);
      float4 wv1 = act ? *reinterpret_cast<const float4*>(w2r1 + c0)
                       : make_float4(0.f, 0.f, 0.f, 0.f);
      #pragma unroll
      for (int s = 0; s < 8; s++) {
        float4 gv = *reinterpret_cast<const float4*>(&lg[s * 1024 + c0]);
        a0[s] += wv0.x * gv.x + wv0.y * gv.y + wv0.z * gv.z + wv0.w * gv.w;
        a1[s] += wv1.x * gv.x + wv1.y * gv.y + wv1.z * gv.z + wv1.w * gv.w;
      }
    }
    #pragma unroll
    for (int off = 32; off; off >>= 1) {
      #pragma unroll
      for (int s = 0; s < 8; s++) {
        a0[s] += __shfl_xor(a0[s], off);
        a1[s] += __shfl_xor(a1[s], off);
      }
    }
    #pragma unroll
    for (int s = 0; s < 8; s++) {
      float h0 = hfinal[(size_t)(sbase + s) * H_N + j0];
      float h1 = hfinal[(size_t)(sbase + s) * H_N + j1];
      float v0 = (h0 > 0.f) ? a0[s] : 0.f;
      float v1 = (h1 > 0.f) ? a1[s] : 0.f;
      float q = v0 * v0 + v1 * v1;
      cb += q;
      cw += xq[s] * q;
    }
  }
  if (lane == 0) { wred[w][0] = cw; wred[w][1] = cb; }
  __syncthreads();

  // --- (c)+(d) partial write, arrive, last-arriver final reduce ---
  if (t == 0) {
    float sw = 0.f, sb = 0.f;
    #pragma unroll
    for (int i = 0; i < 8; i++) { sw += wred[i][0]; sb += wred[i][1]; }
    bwd_part[bid * 2 + 0] = sw;    // W1 trace partial
    bwd_part[bid * 2 + 1] = sb;    // b1 trace partial
    if (jt == 0) {
      float s2 = 0.f, sb2 = 0.f;
      #pragma unroll
      for (int i = 0; i < 8; i++) { s2 += hsqS[i] * tnormS[i]; sb2 += tnormS[i]; }
      samp_part[sg * 2 + 0] = s2;  // W2 trace partial
      samp_part[sg * 2 + 1] = sb2; // b2 trace partial
    }
    unsigned int old = __hip_atomic_fetch_add(counter, 1u, __ATOMIC_ACQ_REL,
                                              __HIP_MEMORY_SCOPE_AGENT);
    isLast = (old == 255u);
  }
  __syncthreads();
  if (isLast) {                    // uniform across block
    float w1v = (t < 256) ? bwd_part[t * 2 + 0] : 0.f;
    float b1v = (t < 256) ? bwd_part[t * 2 + 1] : 0.f;
    float w2v = (t < 16) ? samp_part[t * 2 + 0] : 0.f;
    float b2v = (t < 16) ? samp_part[t * 2 + 1] : 0.f;
    w1v = block_sum512(w1v, red);
    b1v = block_sum512(b1v, red);
    w2v = block_sum512(w2v, red);
    b2v = block_sum512(b2v, red);
    if (t == 0) {
      w1v /= 128.0f; b1v /= 128.0f; w2v /= 128.0f; b2v /= 128.0f;
      out[0] = w1v + b1v + w2v + b2v;
      out[1] = w1v;
      out[2] = b1v;
      out[3] = w2v;
      out[4] = b2v;
    }
  }
}

// ---------------------------------------------------------------------------
extern "C" void kernel_launch(void* const* d_in, const int* in_sizes, int n_in,
                              void* d_out, int out_size, void* d_ws, size_t ws_size,
                              hipStream_t stream) {
  const float* X  = (const float*)d_in[0];
  const float* W1 = (const float*)d_in[1];
  const float* b1 = (const float*)d_in[2];
  const float* W2 = (const float*)d_in[3];
  const float* b2 = (const float*)d_in[4];
  float* out = (float*)d_out;

  float* ws        = (float*)d_ws;
  float* hfinal    = ws;                          // 131072
  float* lpart     = hfinal + B_N * H_N;          // NJT * 131072
  float* xsq       = lpart + NJT * LP_STRIDE;     // 128
  float* samp_part = xsq + B_N;                   // 32
  float* bwd_part  = samp_part + 32;              // 512
  unsigned int* counter = (unsigned int*)(bwd_part + 512);

  k_fc1<<<256, 256, 0, stream>>>(X, W1, b1, hfinal, xsq, counter);
  k_fc2<<<256, 256, 0, stream>>>(hfinal, W2, lpart);
  k_mega<<<256, 512, 0, stream>>>(lpart, b2, W2, hfinal, xsq,
                                  samp_part, bwd_part, counter, out);
}

// Round 8
// 98.695 us; speedup vs baseline: 1.8579x; 1.0314x over previous
//
#include <hip/hip_runtime.h>
#include <hip/hip_bf16.h>
#include <stdint.h>
#include <math.h>

#define B_N 128
#define D_N 512
#define H_N 1024
#define C_N 1000
#define CP  1024                 // padded row stride for logit partials / g
#define NJT 4                    // fc2 j-split (4 planes -> 2 MB lpart)
#define LP_STRIDE (B_N * CP)     // one logit-partial plane

// ---------------------------------------------------------------------------
// threefry2x32 (JAX-compatible, 20 rounds) -- verified bit-exact (R1 absmax 0)
// ---------------------------------------------------------------------------
__device__ __forceinline__ uint32_t rotl32(uint32_t v, int r) {
  return (v << r) | (v >> (32 - r));
}

__device__ __forceinline__ void threefry2x32(uint32_t k0, uint32_t k1,
                                             uint32_t x0, uint32_t x1,
                                             uint32_t &o0, uint32_t &o1) {
  uint32_t ks2 = k0 ^ k1 ^ 0x1BD11BDAu;
#define TF_R(r) { x0 += x1; x1 = rotl32(x1, r); x1 ^= x0; }
  x0 += k0; x1 += k1;
  TF_R(13) TF_R(15) TF_R(26) TF_R(6)
  x0 += k1; x1 += ks2 + 1u;
  TF_R(17) TF_R(29) TF_R(16) TF_R(24)
  x0 += ks2; x1 += k0 + 2u;
  TF_R(13) TF_R(15) TF_R(26) TF_R(6)
  x0 += k0; x1 += k1 + 3u;
  TF_R(17) TF_R(29) TF_R(16) TF_R(24)
  x0 += k1; x1 += ks2 + 4u;
  TF_R(13) TF_R(15) TF_R(26) TF_R(6)
  x0 += ks2; x1 += k0 + 5u;
#undef TF_R
  o0 = x0; o1 = x1;
}

__device__ __forceinline__ float gumbel_from_key(uint32_t k0, uint32_t k1, uint32_t i) {
  uint32_t o0, o1;
  threefry2x32(k0, k1, 0u, i, o0, o1);
  uint32_t bits = o0 ^ o1;
  uint32_t fb = (bits >> 9) | 0x3f800000u;
  float f = __uint_as_float(fb) - 1.0f;            // [0, 1)
  const float tiny = 1.1754943508222875e-38f;
  float u = fmaxf(tiny, f * (1.0f - tiny) + tiny); // JAX uniform(minval=tiny)
  return -logf(-logf(u));
}

// ---------------------------------------------------------------------------
__device__ __forceinline__ float wave_sum(float v) {
  #pragma unroll
  for (int o = 32; o; o >>= 1) v += __shfl_xor(v, o);
  return v;
}

__device__ __forceinline__ float block_sum512(float v, float* red) {
  #pragma unroll
  for (int o = 32; o; o >>= 1) v += __shfl_xor(v, o);
  __syncthreads();
  if ((threadIdx.x & 63) == 0) red[threadIdx.x >> 6] = v;
  __syncthreads();
  return red[0] + red[1] + red[2] + red[3] + red[4] + red[5] + red[6] + red[7];
}

__device__ __forceinline__ float block_max512(float v, float* red) {
  #pragma unroll
  for (int o = 32; o; o >>= 1) v = fmaxf(v, __shfl_xor(v, o));
  __syncthreads();
  if ((threadIdx.x & 63) == 0) red[threadIdx.x >> 6] = v;
  __syncthreads();
  float m = red[0];
  #pragma unroll
  for (int w = 1; w < 8; w++) m = fmaxf(m, red[w]);
  return m;
}

// fma4: a += b * s (function, not macro: R4 lesson -- macro param `w` would
// substitute into the `.w` member access).
__device__ __forceinline__ void fma4(float4 &a, const float4 &b, float s) {
  a.x += b.x * s; a.y += b.y * s; a.z += b.z * s; a.w += b.w * s;
}

// ---------------------------------------------------------------------------
// K1: hfinal[128][1024] = X @ W1 + b1 (full K). R7-proven.
// grid 256 = ct(8: 128c) x sg(32: 4s); 256 thr, thread = 1c x 2s.
// XCD = bid%8 = ct -> one 256 KB W1 slab per XCD (L2-resident).
// Also: ct==0 blocks compute xsq; block 0 zeroes the k_bwd arrival counter.
// ---------------------------------------------------------------------------
__global__ __launch_bounds__(256) void k_fc1(const float* __restrict__ X,
                                             const float* __restrict__ W1,
                                             const float* __restrict__ b1,
                                             float* __restrict__ hfinal,
                                             float* __restrict__ xsq,
                                             unsigned int* __restrict__ counter) {
  __shared__ float xs[4 * D_N];   // 8 KB, [s][d]
  int bid = blockIdx.x;
  int ct = bid & 7, sg = bid >> 3;
  int cbase = ct * 128, sbase = sg * 4;
  int t = threadIdx.x;
  if (bid == 0 && t == 0) *counter = 0u;   // reset arrival counter for k_bwd
  #pragma unroll
  for (int k = 0; k < 2; k++) {
    int idx4 = t + k * 256;                // 0..511 float4s
    int s = idx4 >> 7, dq = idx4 & 127;
    *reinterpret_cast<float4*>(&xs[s * D_N + dq * 4]) =
        *reinterpret_cast<const float4*>(&X[(sbase + s) * D_N + dq * 4]);
  }
  __syncthreads();

  int c0 = cbase + (t & 127);
  int spair = (t >> 7) * 2;                // 0 or 2
  const float* W1c = W1 + c0;
  const float* x0p = &xs[(spair + 0) * D_N];
  const float* x1p = &xs[(spair + 1) * D_N];
  float a0 = 0.f, a1 = 0.f;
  float wA[8], wB[8];
  #pragma unroll
  for (int i = 0; i < 8; i++) wA[i] = W1c[(size_t)i * H_N];
  for (int d0 = 0; d0 < D_N; d0 += 16) {
    #pragma unroll
    for (int i = 0; i < 8; i++) wB[i] = W1c[(size_t)((d0 + 8 + i) & (D_N - 1)) * H_N];
    #pragma unroll
    for (int i = 0; i < 8; i++) { a0 += wA[i] * x0p[d0 + i]; a1 += wA[i] * x1p[d0 + i]; }
    #pragma unroll
    for (int i = 0; i < 8; i++) wA[i] = W1c[(size_t)((d0 + 16 + i) & (D_N - 1)) * H_N];
    #pragma unroll
    for (int i = 0; i < 8; i++) { a0 += wB[i] * x0p[d0 + 8 + i]; a1 += wB[i] * x1p[d0 + 8 + i]; }
  }
  float bb = b1[c0];
  hfinal[(size_t)(sbase + spair + 0) * H_N + c0] = a0 + bb;
  hfinal[(size_t)(sbase + spair + 1) * H_N + c0] = a1 + bb;

  if (ct == 0) {                           // xsq for this block's 4 samples
    int s = t >> 6, l = t & 63;            // wave per sample
    float v = 0.f;
    #pragma unroll
    for (int k = 0; k < 8; k++) { float xv = xs[s * D_N + l + k * 64]; v += xv * xv; }
    v = wave_sum(v);
    if (l == 0) xsq[sbase + s] = v;
  }
}

// ---------------------------------------------------------------------------
// K2: lpart[jt][s][c] = partial of relu(hfinal) @ W2 over j in [jt*256,+256).
// grid 256; bid = sg*16 + (jt*4 + ct): sg(16: 16s), jt(4), ct(4: 256c).
// XCD = bid%8 = (jt*4+ct)%8 -> 2 (ct,jt) W2 slabs (512 KB) per XCD.
// 256 thr, thread = 4c x 4s (R5-proven shape). b2 applied in k_sample.
// ---------------------------------------------------------------------------
__global__ __launch_bounds__(256) void k_fc2(const float* __restrict__ hfinal,
                                             const float* __restrict__ W2,
                                             float* __restrict__ lpart) {
  __shared__ float hT[256 * 20];  // [j][s], stride 20; 20 KB
  int bid = blockIdx.x;
  int q = bid & 15;
  int ct = q & 3, jt = q >> 2, sg = bid >> 4;
  int cbase = ct * 256, sbase = sg * 16, jbase = jt * 256;
  int t = threadIdx.x;
  #pragma unroll
  for (int k = 0; k < 16; k++) {
    int idx = t + k * 256;        // 0..4095
    int s = idx >> 8, j = idx & 255;   // lanes sweep j -> coalesced hfinal rows
    hT[j * 20 + s] = fmaxf(hfinal[(size_t)(sbase + s) * H_N + jbase + j], 0.0f);
  }
  __syncthreads();
  int c4 = cbase + (t & 63) * 4;
  int s4 = (t >> 6) * 4;
  int cr = (c4 <= C_N - 4) ? c4 : (C_N - 4);   // clamp reads; writes stay at c4
  float4 acc0 = {0,0,0,0}, acc1 = {0,0,0,0}, acc2 = {0,0,0,0}, acc3 = {0,0,0,0};
  const float* W2c = W2 + (size_t)jbase * C_N + cr;
  float4 wb[4], wn[4];
  #pragma unroll
  for (int i = 0; i < 4; i++)
    wb[i] = *reinterpret_cast<const float4*>(W2c + (size_t)i * C_N);
  for (int j0 = 0; j0 < 256; j0 += 4) {
    #pragma unroll
    for (int i = 0; i < 4; i++) {
      int jn = j0 + 4 + i; jn = (jn < 256) ? jn : 255;
      wn[i] = *reinterpret_cast<const float4*>(W2c + (size_t)jn * C_N);
    }
    #pragma unroll
    for (int i = 0; i < 4; i++) {
      float4 xv = *reinterpret_cast<const float4*>(&hT[(j0 + i) * 20 + s4]);
      fma4(acc0, wb[i], xv.x);
      fma4(acc1, wb[i], xv.y);
      fma4(acc2, wb[i], xv.z);
      fma4(acc3, wb[i], xv.w);
    }
    #pragma unroll
    for (int i = 0; i < 4; i++) wb[i] = wn[i];
  }
  float* lp = lpart + (size_t)jt * LP_STRIDE;
  *reinterpret_cast<float4*>(&lp[(size_t)(sbase + s4 + 0) * CP + c4]) = acc0;
  *reinterpret_cast<float4*>(&lp[(size_t)(sbase + s4 + 1) * CP + c4]) = acc1;
  *reinterpret_cast<float4*>(&lp[(size_t)(sbase + s4 + 2) * CP + c4]) = acc2;
  *reinterpret_cast<float4*>(&lp[(size_t)(sbase + s4 + 3) * CP + c4]) = acc3;
}

// ---------------------------------------------------------------------------
// K3: sum NJT logit partials + b2; categorical sample (threefry bit-exact);
// softmax grad g -> global (zero-padded to CP); W2/b2 trace partials.
// One block (512 thr) per sample. Verbatim R5 math, 4 planes.
// ---------------------------------------------------------------------------
__global__ __launch_bounds__(512) void k_sample(const float* __restrict__ lpart,
                                                const float* __restrict__ b2,
                                                const float* __restrict__ hfinal,
                                                float* __restrict__ g,
                                                float* __restrict__ samp_part) {
  __shared__ float lg[C_N];
  __shared__ float red[8];
  __shared__ float redv[8];
  __shared__ int   redi[8];
  __shared__ uint32_t keys[2];
  int b = blockIdx.x;
  int t = threadIdx.x;
  {
    float sA = b2[t];
    float sB = (t + 512 < C_N) ? b2[t + 512] : 0.f;
    #pragma unroll
    for (int p = 0; p < NJT; p++) {
      const float* lp = lpart + (size_t)p * LP_STRIDE + (size_t)b * CP;
      sA += lp[t];
      if (t + 512 < C_N) sB += lp[t + 512];
    }
    lg[t] = sA;
    if (t + 512 < C_N) lg[t + 512] = sB;
  }
  if (t == 0) {
    uint32_t o0, o1;
    threefry2x32(0u, 42u, 0u, (uint32_t)b, o0, o1);
    keys[0] = o0; keys[1] = o1;
  }
  __syncthreads();
  uint32_t k0 = keys[0], k1 = keys[1];
  float bz = -INFINITY; int bi = 0x7fffffff;
  {
    float z0 = lg[t] + gumbel_from_key(k0, k1, (uint32_t)t);
    bz = z0; bi = t;
    if (t + 512 < C_N) {
      float z1 = lg[t + 512] + gumbel_from_key(k0, k1, (uint32_t)(t + 512));
      if (z1 > bz || (z1 == bz && (t + 512) < bi)) { bz = z1; bi = t + 512; }
    }
  }
  #pragma unroll
  for (int o = 32; o; o >>= 1) {
    float ov = __shfl_xor(bz, o);
    int   oi = __shfl_xor(bi, o);
    if (ov > bz || (ov == bz && oi < bi)) { bz = ov; bi = oi; }
  }
  if ((t & 63) == 0) { redv[t >> 6] = bz; redi[t >> 6] = bi; }
  __syncthreads();
  if (t == 0) {
    #pragma unroll
    for (int w = 1; w < 8; w++) {
      if (redv[w] > redv[0] || (redv[w] == redv[0] && redi[w] < redi[0])) {
        redv[0] = redv[w]; redi[0] = redi[w];
      }
    }
  }
  __syncthreads();
  int y = redi[0];
  float lm = lg[t];
  if (t + 512 < C_N) lm = fmaxf(lm, lg[t + 512]);
  float m = block_max512(lm, red);
  float ea = expf(lg[t] - m);
  float eb = (t + 512 < C_N) ? expf(lg[t + 512] - m) : 0.0f;
  float sum1 = block_sum512(ea + eb, red);
  float inv = 1.0f / sum1;
  float ga  = ea * inv - ((t == y) ? 1.0f : 0.0f);
  float gb2 = eb * inv - (((t + 512) == y) ? 1.0f : 0.0f);
  g[(size_t)b * CP + t] = ga;
  g[(size_t)b * CP + t + 512] = (t + 512 < C_N) ? gb2 : 0.0f;  // zero pads
  float gn = ga * ga + ((t + 512 < C_N) ? gb2 * gb2 : 0.0f);
  float tnorm = block_sum512(gn, red);   // ||g||^2

  float h0 = hfinal[(size_t)b * H_N + t];
  float h1 = hfinal[(size_t)b * H_N + t + 512];
  float r0 = fmaxf(h0, 0.f), r1 = fmaxf(h1, 0.f);
  float hsq = block_sum512(r0 * r0 + r1 * r1, red);

  if (t == 0) {
    samp_part[b * 2 + 0] = hsq * tnorm;  // W2 trace numerator
    samp_part[b * 2 + 1] = tnorm;        // b2 trace numerator
  }
}

// ---------------------------------------------------------------------------
// K4: backward ghat = g @ W2^T slice, fused mask/square/trace, arrival-counter
// final reduce (R7-proven idiom). grid 512 = sg(16) x jt(32: 32 j-rows);
// 512 thr -> 2 blocks/CU. XCD = bid%8 = jt%8 -> 4 jts (512 KB W2) per XCD.
// ---------------------------------------------------------------------------
__global__ __launch_bounds__(512) void k_bwd(const float* __restrict__ g,
                                             const float* __restrict__ W2,
                                             const float* __restrict__ hfinal,
                                             const float* __restrict__ xsq_g,
                                             const float* __restrict__ samp_part,
                                             float* __restrict__ bwd_part,
                                             unsigned int* __restrict__ counter,
                                             float* __restrict__ out) {
  __shared__ float gs[8 * 1024];  // 32 KB
  __shared__ float xq[8];
  __shared__ float wred[8][2];
  __shared__ float red[8];
  __shared__ int isLast;
  int bid = blockIdx.x;
  int jt = bid & 31, sg = bid >> 5;
  int sbase = sg * 8, jbase = jt * 32;
  int t = threadIdx.x, w = t >> 6, lane = t & 63;
  #pragma unroll
  for (int k = 0; k < 16; k++) {
    int idx = t + k * 512;            // 0..8191
    gs[idx] = g[(size_t)(sbase + (idx >> 10)) * CP + (idx & 1023)];
  }
  if (t < 8) xq[t] = xsq_g[sbase + t];
  __syncthreads();

  float cb = 0.f, cw = 0.f;
  #pragma unroll
  for (int it2 = 0; it2 < 2; it2++) {
    int jb = jbase + it2 * 16;
    int j0 = jb + w * 2, j1 = j0 + 1;
    float a0[8] = {0,0,0,0,0,0,0,0};
    float a1[8] = {0,0,0,0,0,0,0,0};
    const float* w2r0 = W2 + (size_t)j0 * C_N;
    const float* w2r1 = W2 + (size_t)j1 * C_N;
    #pragma unroll
    for (int it = 0; it < 4; it++) {
      int c0 = it * 256 + lane * 4;
      bool act = (c0 < C_N);
      float4 wv0 = act ? *reinterpret_cast<const float4*>(w2r0 + c0)
                       : make_float4(0.f, 0.f, 0.f, 0.f);
      float4 wv1 = act ? *reinterpret_cast<const float4*>(w2r1 + c0)
                       : make_float4(0.f, 0.f, 0.f, 0.f);
      #pragma unroll
      for (int s = 0; s < 8; s++) {
        float4 gv = *reinterpret_cast<const float4*>(&gs[s * 1024 + c0]);
        a0[s] += wv0.x * gv.x + wv0.y * gv.y + wv0.z * gv.z + wv0.w * gv.w;
        a1[s] += wv1.x * gv.x + wv1.y * gv.y + wv1.z * gv.z + wv1.w * gv.w;
      }
    }
    #pragma unroll
    for (int off = 32; off; off >>= 1) {
      #pragma unroll
      for (int s = 0; s < 8; s++) {
        a0[s] += __shfl_xor(a0[s], off);
        a1[s] += __shfl_xor(a1[s], off);
      }
    }
    #pragma unroll
    for (int s = 0; s < 8; s++) {
      float h0 = hfinal[(size_t)(sbase + s) * H_N + j0];
      float h1 = hfinal[(size_t)(sbase + s) * H_N + j1];
      float v0 = (h0 > 0.f) ? a0[s] : 0.f;
      float v1 = (h1 > 0.f) ? a1[s] : 0.f;
      float q = v0 * v0 + v1 * v1;
      cb += q;
      cw += xq[s] * q;
    }
  }
  if (lane == 0) { wred[w][0] = cw; wred[w][1] = cb; }
  __syncthreads();

  if (t == 0) {
    float sw = 0.f, sb = 0.f;
    #pragma unroll
    for (int i = 0; i < 8; i++) { sw += wred[i][0]; sb += wred[i][1]; }
    bwd_part[bid * 2 + 0] = sw;    // W1 trace partial
    bwd_part[bid * 2 + 1] = sb;    // b1 trace partial
    unsigned int old = __hip_atomic_fetch_add(counter, 1u, __ATOMIC_ACQ_REL,
                                              __HIP_MEMORY_SCOPE_AGENT);
    isLast = (old == 511u);
  }
  __syncthreads();
  if (isLast) {                    // uniform across block
    float w1v = bwd_part[t * 2 + 0];
    float b1v = bwd_part[t * 2 + 1];
    float w2v = (t < B_N) ? samp_part[t * 2 + 0] : 0.f;
    float b2v = (t < B_N) ? samp_part[t * 2 + 1] : 0.f;
    w1v = block_sum512(w1v, red);
    b1v = block_sum512(b1v, red);
    w2v = block_sum512(w2v, red);
    b2v = block_sum512(b2v, red);
    if (t == 0) {
      w1v /= 128.0f; b1v /= 128.0f; w2v /= 128.0f; b2v /= 128.0f;
      out[0] = w1v + b1v + w2v + b2v;
      out[1] = w1v;
      out[2] = b1v;
      out[3] = w2v;
      out[4] = b2v;
    }
  }
}

// ---------------------------------------------------------------------------
extern "C" void kernel_launch(void* const* d_in, const int* in_sizes, int n_in,
                              void* d_out, int out_size, void* d_ws, size_t ws_size,
                              hipStream_t stream) {
  const float* X  = (const float*)d_in[0];
  const float* W1 = (const float*)d_in[1];
  const float* b1 = (const float*)d_in[2];
  const float* W2 = (const float*)d_in[3];
  const float* b2 = (const float*)d_in[4];
  float* out = (float*)d_out;

  float* ws        = (float*)d_ws;
  float* hfinal    = ws;                          // 131072
  float* lpart     = hfinal + B_N * H_N;          // NJT * 131072 (2 MB)
  float* g         = lpart + NJT * LP_STRIDE;     // 131072
  float* xsq       = g + B_N * CP;                // 128
  float* samp_part = xsq + B_N;                   // 256
  float* bwd_part  = samp_part + 256;             // 1024
  unsigned int* counter = (unsigned int*)(bwd_part + 1024);

  k_fc1<<<256, 256, 0, stream>>>(X, W1, b1, hfinal, xsq, counter);
  k_fc2<<<256, 256, 0, stream>>>(hfinal, W2, lpart);
  k_sample<<<B_N, 512, 0, stream>>>(lpart, b2, hfinal, g, samp_part);
  k_bwd<<<512, 512, 0, stream>>>(g, W2, hfinal, xsq, samp_part,
                                 bwd_part, counter, out);
}

// Round 9
// 65.976 us; speedup vs baseline: 2.7792x; 1.4959x over previous
//
#include <hip/hip_runtime.h>
#include <hip/hip_bf16.h>
#include <stdint.h>
#include <math.h>

#define B_N 128
#define D_N 512
#define H_N 1024
#define C_N 1000
#define CP  1024                 // padded row stride for logit partials / g
#define NJT 16                   // fc2 j-split (16 planes, K=64 -- R5-proven order)
#define LP_STRIDE (B_N * CP)     // one logit-partial plane

// ---------------------------------------------------------------------------
// threefry2x32 (JAX-compatible, 20 rounds) -- verified bit-exact (R1 absmax 0)
// ---------------------------------------------------------------------------
__device__ __forceinline__ uint32_t rotl32(uint32_t v, int r) {
  return (v << r) | (v >> (32 - r));
}

__device__ __forceinline__ void threefry2x32(uint32_t k0, uint32_t k1,
                                             uint32_t x0, uint32_t x1,
                                             uint32_t &o0, uint32_t &o1) {
  uint32_t ks2 = k0 ^ k1 ^ 0x1BD11BDAu;
#define TF_R(r) { x0 += x1; x1 = rotl32(x1, r); x1 ^= x0; }
  x0 += k0; x1 += k1;
  TF_R(13) TF_R(15) TF_R(26) TF_R(6)
  x0 += k1; x1 += ks2 + 1u;
  TF_R(17) TF_R(29) TF_R(16) TF_R(24)
  x0 += ks2; x1 += k0 + 2u;
  TF_R(13) TF_R(15) TF_R(26) TF_R(6)
  x0 += k0; x1 += k1 + 3u;
  TF_R(17) TF_R(29) TF_R(16) TF_R(24)
  x0 += k1; x1 += ks2 + 4u;
  TF_R(13) TF_R(15) TF_R(26) TF_R(6)
  x0 += ks2; x1 += k0 + 5u;
#undef TF_R
  o0 = x0; o1 = x1;
}

__device__ __forceinline__ float gumbel_from_key(uint32_t k0, uint32_t k1, uint32_t i) {
  uint32_t o0, o1;
  threefry2x32(k0, k1, 0u, i, o0, o1);
  uint32_t bits = o0 ^ o1;
  uint32_t fb = (bits >> 9) | 0x3f800000u;
  float f = __uint_as_float(fb) - 1.0f;            // [0, 1)
  const float tiny = 1.1754943508222875e-38f;
  float u = fmaxf(tiny, f * (1.0f - tiny) + tiny); // JAX uniform(minval=tiny)
  return -logf(-logf(u));
}

// ---------------------------------------------------------------------------
__device__ __forceinline__ float wave_sum(float v) {
  #pragma unroll
  for (int o = 32; o; o >>= 1) v += __shfl_xor(v, o);
  return v;
}

__device__ __forceinline__ float block_sum512(float v, float* red) {
  #pragma unroll
  for (int o = 32; o; o >>= 1) v += __shfl_xor(v, o);
  __syncthreads();
  if ((threadIdx.x & 63) == 0) red[threadIdx.x >> 6] = v;
  __syncthreads();
  return red[0] + red[1] + red[2] + red[3] + red[4] + red[5] + red[6] + red[7];
}

__device__ __forceinline__ float block_max512(float v, float* red) {
  #pragma unroll
  for (int o = 32; o; o >>= 1) v = fmaxf(v, __shfl_xor(v, o));
  __syncthreads();
  if ((threadIdx.x & 63) == 0) red[threadIdx.x >> 6] = v;
  __syncthreads();
  float m = red[0];
  #pragma unroll
  for (int w = 1; w < 8; w++) m = fmaxf(m, red[w]);
  return m;
}

// fma4: a += b * s (function, not macro: R4 lesson -- macro param `w` would
// substitute into the `.w` member access).
__device__ __forceinline__ void fma4(float4 &a, const float4 &b, float s) {
  a.x += b.x * s; a.y += b.y * s; a.z += b.z * s; a.w += b.w * s;
}

// ---------------------------------------------------------------------------
// K1: hfinal[128][1024] = X @ W1 + b1 (full K).
// grid 512 = ct(8: 128c) x sg(64: 2s); 256 thr -> 2 blocks/CU (2 waves/SIMD).
// XCD = bid%8 = ct -> one 256 KB W1 slab per XCD (L2-resident).
// 8-deep scalar prefetch (wA/wB). ct==0 blocks also compute xsq; block 0
// zeroes the k_bwd arrival counter.
// ---------------------------------------------------------------------------
__global__ __launch_bounds__(256) void k_fc1(const float* __restrict__ X,
                                             const float* __restrict__ W1,
                                             const float* __restrict__ b1,
                                             float* __restrict__ hfinal,
                                             float* __restrict__ xsq,
                                             unsigned int* __restrict__ counter) {
  __shared__ float xs[2 * D_N];   // 4 KB, [s][d]
  int bid = blockIdx.x;
  int ct = bid & 7, sg = bid >> 3;          // sg 0..63
  int cbase = ct * 128, sbase = sg * 2;
  int t = threadIdx.x;
  if (bid == 0 && t == 0) *counter = 0u;    // reset arrival counter for k_bwd
  {
    int s = t >> 7, dq = t & 127;           // 256 float4s = 2 rows
    *reinterpret_cast<float4*>(&xs[s * D_N + dq * 4]) =
        *reinterpret_cast<const float4*>(&X[(size_t)(sbase + s) * D_N + dq * 4]);
  }
  __syncthreads();

  int c0 = cbase + (t & 127);
  int sp = t >> 7;                          // 0 or 1
  const float* W1c = W1 + c0;
  const float* xp = &xs[sp * D_N];
  float a0 = 0.f;
  float wA[8], wB[8];
  #pragma unroll
  for (int i = 0; i < 8; i++) wA[i] = W1c[(size_t)i * H_N];
  for (int d0 = 0; d0 < D_N; d0 += 16) {
    #pragma unroll
    for (int i = 0; i < 8; i++) wB[i] = W1c[(size_t)((d0 + 8 + i) & (D_N - 1)) * H_N];
    #pragma unroll
    for (int i = 0; i < 8; i++) a0 += wA[i] * xp[d0 + i];
    #pragma unroll
    for (int i = 0; i < 8; i++) wA[i] = W1c[(size_t)((d0 + 16 + i) & (D_N - 1)) * H_N];
    #pragma unroll
    for (int i = 0; i < 8; i++) a0 += wB[i] * xp[d0 + 8 + i];
  }
  hfinal[(size_t)(sbase + sp) * H_N + c0] = a0 + b1[c0];

  if (ct == 0) {                            // xsq for this block's 2 samples
    int w = t >> 6, l = t & 63;
    if (w < 2) {
      float v = 0.f;
      #pragma unroll
      for (int k = 0; k < 8; k++) { float xv = xs[w * D_N + l + k * 64]; v += xv * xv; }
      v = wave_sum(v);
      if (l == 0) xsq[sbase + w] = v;
    }
  }
}

// ---------------------------------------------------------------------------
// K2: lpart[jt][s][c] = partial of relu(hfinal) @ W2 over j in [jt*64,+64).
// grid 512; bid = sg*64 + jt*4 + ct: ct(4: 256c), jt(16), sg(8: 16s).
// 256 thr, thread = 4c x 4s (R5-proven). 2 blocks/CU. XCD = bid%8 =
// (jt*4+ct)%8 -> 8 sg-blocks share each 64 KB W2 slab in one XCD's L2.
// 3-buffer pipeline (A/B compute, T prefetch) -> ~8 float4 loads in flight.
// b2 applied in k_sample.
// ---------------------------------------------------------------------------
__global__ __launch_bounds__(256) void k_fc2(const float* __restrict__ hfinal,
                                             const float* __restrict__ W2,
                                             float* __restrict__ lpart) {
  __shared__ float hT[64 * 20];   // [j][s], stride 20; 5 KB
  int bid = blockIdx.x;
  int ct = bid & 3, jt = (bid >> 2) & 15, sg = bid >> 6;
  int cbase = ct * 256, jbase = jt * 64, sbase = sg * 16;
  int t = threadIdx.x;
  #pragma unroll
  for (int k = 0; k < 4; k++) {
    int idx = t + k * 256;        // 0..1023 = 64j x 16s, lanes sweep j
    int s = idx >> 6, j = idx & 63;
    hT[j * 20 + s] = fmaxf(hfinal[(size_t)(sbase + s) * H_N + jbase + j], 0.0f);
  }
  __syncthreads();
  int c4 = cbase + (t & 63) * 4;
  int s4 = (t >> 6) * 4;
  if (c4 < C_N) {
    const float* W2p = W2 + (size_t)jbase * C_N + c4;
    float4 A[4], Bb[4], T[4];
    #pragma unroll
    for (int i = 0; i < 4; i++)
      A[i] = *reinterpret_cast<const float4*>(W2p + (size_t)i * C_N);
    #pragma unroll
    for (int i = 0; i < 4; i++)
      Bb[i] = *reinterpret_cast<const float4*>(W2p + (size_t)(4 + i) * C_N);
    float4 acc0 = {0,0,0,0}, acc1 = {0,0,0,0}, acc2 = {0,0,0,0}, acc3 = {0,0,0,0};
    for (int j0 = 0; j0 < 64; j0 += 8) {
      #pragma unroll
      for (int i = 0; i < 4; i++) {
        int jn = (j0 + 8 + i) & 63;
        T[i] = *reinterpret_cast<const float4*>(W2p + (size_t)jn * C_N);
      }
      #pragma unroll
      for (int i = 0; i < 4; i++) {
        float4 xv = *reinterpret_cast<const float4*>(&hT[(j0 + i) * 20 + s4]);
        fma4(acc0, A[i], xv.x);
        fma4(acc1, A[i], xv.y);
        fma4(acc2, A[i], xv.z);
        fma4(acc3, A[i], xv.w);
      }
      #pragma unroll
      for (int i = 0; i < 4; i++) A[i] = T[i];
      #pragma unroll
      for (int i = 0; i < 4; i++) {
        int jn = (j0 + 12 + i) & 63;
        T[i] = *reinterpret_cast<const float4*>(W2p + (size_t)jn * C_N);
      }
      #pragma unroll
      for (int i = 0; i < 4; i++) {
        float4 xv = *reinterpret_cast<const float4*>(&hT[(j0 + 4 + i) * 20 + s4]);
        fma4(acc0, Bb[i], xv.x);
        fma4(acc1, Bb[i], xv.y);
        fma4(acc2, Bb[i], xv.z);
        fma4(acc3, Bb[i], xv.w);
      }
      #pragma unroll
      for (int i = 0; i < 4; i++) Bb[i] = T[i];
    }
    float* lp = lpart + (size_t)jt * LP_STRIDE;
    *reinterpret_cast<float4*>(&lp[(size_t)(sbase + s4 + 0) * CP + c4]) = acc0;
    *reinterpret_cast<float4*>(&lp[(size_t)(sbase + s4 + 1) * CP + c4]) = acc1;
    *reinterpret_cast<float4*>(&lp[(size_t)(sbase + s4 + 2) * CP + c4]) = acc2;
    *reinterpret_cast<float4*>(&lp[(size_t)(sbase + s4 + 3) * CP + c4]) = acc3;
  }
}

// ---------------------------------------------------------------------------
// K3: sum NJT logit partials + b2 (R5-proven order, p=0..15 ascending);
// categorical sample (threefry bit-exact); softmax grad g -> global
// (zero-padded to CP); W2/b2 trace partials. One block (512 thr) per sample.
// ---------------------------------------------------------------------------
__global__ __launch_bounds__(512) void k_sample(const float* __restrict__ lpart,
                                                const float* __restrict__ b2,
                                                const float* __restrict__ hfinal,
                                                float* __restrict__ g,
                                                float* __restrict__ samp_part) {
  __shared__ float lg[C_N];
  __shared__ float red[8];
  __shared__ float redv[8];
  __shared__ int   redi[8];
  __shared__ uint32_t keys[2];
  int b = blockIdx.x;
  int t = threadIdx.x;
  {
    float sA = b2[t];
    float sB = (t + 512 < C_N) ? b2[t + 512] : 0.f;
    #pragma unroll
    for (int p = 0; p < NJT; p++) {
      const float* lp = lpart + (size_t)p * LP_STRIDE + (size_t)b * CP;
      sA += lp[t];
      if (t + 512 < C_N) sB += lp[t + 512];
    }
    lg[t] = sA;
    if (t + 512 < C_N) lg[t + 512] = sB;
  }
  if (t == 0) {
    uint32_t o0, o1;
    threefry2x32(0u, 42u, 0u, (uint32_t)b, o0, o1);
    keys[0] = o0; keys[1] = o1;
  }
  __syncthreads();
  uint32_t k0 = keys[0], k1 = keys[1];
  float bz = -INFINITY; int bi = 0x7fffffff;
  {
    float z0 = lg[t] + gumbel_from_key(k0, k1, (uint32_t)t);
    bz = z0; bi = t;
    if (t + 512 < C_N) {
      float z1 = lg[t + 512] + gumbel_from_key(k0, k1, (uint32_t)(t + 512));
      if (z1 > bz || (z1 == bz && (t + 512) < bi)) { bz = z1; bi = t + 512; }
    }
  }
  #pragma unroll
  for (int o = 32; o; o >>= 1) {
    float ov = __shfl_xor(bz, o);
    int   oi = __shfl_xor(bi, o);
    if (ov > bz || (ov == bz && oi < bi)) { bz = ov; bi = oi; }
  }
  if ((t & 63) == 0) { redv[t >> 6] = bz; redi[t >> 6] = bi; }
  __syncthreads();
  if (t == 0) {
    #pragma unroll
    for (int w = 1; w < 8; w++) {
      if (redv[w] > redv[0] || (redv[w] == redv[0] && redi[w] < redi[0])) {
        redv[0] = redv[w]; redi[0] = redi[w];
      }
    }
  }
  __syncthreads();
  int y = redi[0];
  float lm = lg[t];
  if (t + 512 < C_N) lm = fmaxf(lm, lg[t + 512]);
  float m = block_max512(lm, red);
  float ea = expf(lg[t] - m);
  float eb = (t + 512 < C_N) ? expf(lg[t + 512] - m) : 0.0f;
  float sum1 = block_sum512(ea + eb, red);
  float inv = 1.0f / sum1;
  float ga  = ea * inv - ((t == y) ? 1.0f : 0.0f);
  float gb2 = eb * inv - (((t + 512) == y) ? 1.0f : 0.0f);
  g[(size_t)b * CP + t] = ga;
  g[(size_t)b * CP + t + 512] = (t + 512 < C_N) ? gb2 : 0.0f;  // zero pads
  float gn = ga * ga + ((t + 512 < C_N) ? gb2 * gb2 : 0.0f);
  float tnorm = block_sum512(gn, red);   // ||g||^2

  float h0 = hfinal[(size_t)b * H_N + t];
  float h1 = hfinal[(size_t)b * H_N + t + 512];
  float r0 = fmaxf(h0, 0.f), r1 = fmaxf(h1, 0.f);
  float hsq = block_sum512(r0 * r0 + r1 * r1, red);

  if (t == 0) {
    samp_part[b * 2 + 0] = hsq * tnorm;  // W2 trace numerator
    samp_part[b * 2 + 1] = tnorm;        // b2 trace numerator
  }
}

// ---------------------------------------------------------------------------
// K4: backward ghat = g @ W2^T slice, fused mask/square/trace, arrival-counter
// final reduce (R7-proven idiom). grid 512 = sg(16) x jt(32: 32 j-rows);
// 512 thr -> 16 waves/CU. XCD = bid%8 = jt%8 -> 4 jts (512 KB W2) per XCD.
// ---------------------------------------------------------------------------
__global__ __launch_bounds__(512) void k_bwd(const float* __restrict__ g,
                                             const float* __restrict__ W2,
                                             const float* __restrict__ hfinal,
                                             const float* __restrict__ xsq_g,
                                             const float* __restrict__ samp_part,
                                             float* __restrict__ bwd_part,
                                             unsigned int* __restrict__ counter,
                                             float* __restrict__ out) {
  __shared__ float gs[8 * 1024];  // 32 KB
  __shared__ float xq[8];
  __shared__ float wred[8][2];
  __shared__ float red[8];
  __shared__ int isLast;
  int bid = blockIdx.x;
  int jt = bid & 31, sg = bid >> 5;
  int sbase = sg * 8, jbase = jt * 32;
  int t = threadIdx.x, w = t >> 6, lane = t & 63;
  #pragma unroll
  for (int k = 0; k < 16; k++) {
    int idx = t + k * 512;            // 0..8191
    gs[idx] = g[(size_t)(sbase + (idx >> 10)) * CP + (idx & 1023)];
  }
  if (t < 8) xq[t] = xsq_g[sbase + t];
  __syncthreads();

  float cb = 0.f, cw = 0.f;
  #pragma unroll
  for (int it2 = 0; it2 < 2; it2++) {
    int jb = jbase + it2 * 16;
    int j0 = jb + w * 2, j1 = j0 + 1;
    float a0[8] = {0,0,0,0,0,0,0,0};
    float a1[8] = {0,0,0,0,0,0,0,0};
    const float* w2r0 = W2 + (size_t)j0 * C_N;
    const float* w2r1 = W2 + (size_t)j1 * C_N;
    #pragma unroll
    for (int it = 0; it < 4; it++) {
      int c0 = it * 256 + lane * 4;
      bool act = (c0 < C_N);
      float4 wv0 = act ? *reinterpret_cast<const float4*>(w2r0 + c0)
                       : make_float4(0.f, 0.f, 0.f, 0.f);
      float4 wv1 = act ? *reinterpret_cast<const float4*>(w2r1 + c0)
                       : make_float4(0.f, 0.f, 0.f, 0.f);
      #pragma unroll
      for (int s = 0; s < 8; s++) {
        float4 gv = *reinterpret_cast<const float4*>(&gs[s * 1024 + c0]);
        a0[s] += wv0.x * gv.x + wv0.y * gv.y + wv0.z * gv.z + wv0.w * gv.w;
        a1[s] += wv1.x * gv.x + wv1.y * gv.y + wv1.z * gv.z + wv1.w * gv.w;
      }
    }
    #pragma unroll
    for (int off = 32; off; off >>= 1) {
      #pragma unroll
      for (int s = 0; s < 8; s++) {
        a0[s] += __shfl_xor(a0[s], off);
        a1[s] += __shfl_xor(a1[s], off);
      }
    }
    #pragma unroll
    for (int s = 0; s < 8; s++) {
      float h0 = hfinal[(size_t)(sbase + s) * H_N + j0];
      float h1 = hfinal[(size_t)(sbase + s) * H_N + j1];
      float v0 = (h0 > 0.f) ? a0[s] : 0.f;
      float v1 = (h1 > 0.f) ? a1[s] : 0.f;
      float q = v0 * v0 + v1 * v1;
      cb += q;
      cw += xq[s] * q;
    }
  }
  if (lane == 0) { wred[w][0] = cw; wred[w][1] = cb; }
  __syncthreads();

  if (t == 0) {
    float sw = 0.f, sb = 0.f;
    #pragma unroll
    for (int i = 0; i < 8; i++) { sw += wred[i][0]; sb += wred[i][1]; }
    bwd_part[bid * 2 + 0] = sw;    // W1 trace partial
    bwd_part[bid * 2 + 1] = sb;    // b1 trace partial
    unsigned int old = __hip_atomic_fetch_add(counter, 1u, __ATOMIC_ACQ_REL,
                                              __HIP_MEMORY_SCOPE_AGENT);
    isLast = (old == 511u);
  }
  __syncthreads();
  if (isLast) {                    // uniform across block
    float w1v = bwd_part[t * 2 + 0];
    float b1v = bwd_part[t * 2 + 1];
    float w2v = (t < B_N) ? samp_part[t * 2 + 0] : 0.f;
    float b2v = (t < B_N) ? samp_part[t * 2 + 1] : 0.f;
    w1v = block_sum512(w1v, red);
    b1v = block_sum512(b1v, red);
    w2v = block_sum512(w2v, red);
    b2v = block_sum512(b2v, red);
    if (t == 0) {
      w1v /= 128.0f; b1v /= 128.0f; w2v /= 128.0f; b2v /= 128.0f;
      out[0] = w1v + b1v + w2v + b2v;
      out[1] = w1v;
      out[2] = b1v;
      out[3] = w2v;
      out[4] = b2v;
    }
  }
}

// ---------------------------------------------------------------------------
extern "C" void kernel_launch(void* const* d_in, const int* in_sizes, int n_in,
                              void* d_out, int out_size, void* d_ws, size_t ws_size,
                              hipStream_t stream) {
  const float* X  = (const float*)d_in[0];
  const float* W1 = (const float*)d_in[1];
  const float* b1 = (const float*)d_in[2];
  const float* W2 = (const float*)d_in[3];
  const float* b2 = (const float*)d_in[4];
  float* out = (float*)d_out;

  float* ws        = (float*)d_ws;
  float* hfinal    = ws;                          // 131072
  float* lpart     = hfinal + B_N * H_N;          // NJT * 131072 (8 MB)
  float* g         = lpart + NJT * LP_STRIDE;     // 131072
  float* xsq       = g + B_N * CP;                // 128
  float* samp_part = xsq + B_N;                   // 256
  float* bwd_part  = samp_part + 256;             // 1024
  unsigned int* counter = (unsigned int*)(bwd_part + 1024);

  k_fc1<<<512, 256, 0, stream>>>(X, W1, b1, hfinal, xsq, counter);
  k_fc2<<<512, 256, 0, stream>>>(hfinal, W2, lpart);
  k_sample<<<B_N, 512, 0, stream>>>(lpart, b2, hfinal, g, samp_part);
  k_bwd<<<512, 512, 0, stream>>>(g, W2, hfinal, xsq, samp_part,
                                 bwd_part, counter, out);
}